// Round 2
// baseline (847.756 us; speedup 1.0000x reference)
//
#include <hip/hip_runtime.h>

// SSIM loss — barrier-free streaming separable conv, v2 (resubmit; R1 bench
// failed with a container-acquire infra error, no kernel signal).
// Changes vs v1 (122 us stream kernel, VALUBusy 32%, Occ 16%, 1.3e7 LDS conflicts):
//  - SROWS 32 -> 16: 6144 one-wave blocks (24/CU available) vs 3072 (12/CU).
//    Latency-bound regime: 2x wave concurrency beats +24% halo work.
//  - Skewed LDS layout: pair xr -> xr + (xr>>4). Breaks the stride-4-word
//    read pattern (8 lanes/bank) and stride-8-word write pattern (9-way)
//    down to ~2-way (free per m136). 12 read offsets precomputed per lane.
//  - Write-ahead staging: step s stages row s+1 into buf[par^1] and reads
//    buf[par] (written a full step earlier) -> removes the in-step
//    write->wait->read->wait LDS round trip. DS ops are in-order per wave;
//    single-wave blocks, so no barrier needed.
//  - Finalize fused into stream kernel (last-block-done), one less launch.

typedef float v2f __attribute__((ext_vector_type(2)));

#define IMG    512
#define SCOLS  128          // cols per strip (2 per lane)
#define SROWS  16           // output rows per strip
#define NSTEPS 26           // SROWS + 10 halo rows
#define BUFW   304          // skewed: 144 pairs + 8 pad pairs = 152 pairs = 304 words
#define NBLOCKS (4 * 32 * 48)
#define NPIX   (16.0f * 3.0f * 512.0f * 512.0f)

__device__ __forceinline__ float clamp01(float x) {
    // fmaxf(NaN,0) -> 0: nan_to_num + clip(0,1) in two ops
    return fminf(fmaxf(x, 0.0f), 1.0f);
}

__device__ __forceinline__ float ssim_px(v2f mu, v2f e, float e12, float C1, float C2) {
    v2f musq = mu * mu;                       // {mu1^2, mu2^2}  (pk_mul)
    float mu12 = mu.x * mu.y;
    v2f sig = e - musq;                       // {sig1, sig2}
    v2f lo = {1e-6f, 1e-6f};
    v2f hi = {1e6f, 1e6f};
    sig = __builtin_elementwise_max(sig, lo);
    sig = __builtin_elementwise_min(sig, hi);
    float s12 = e12 - mu12;
    float num = fmaf(2.f, mu12, C1) * fmaf(2.f, s12, C2);
    float den = (musq.x + musq.y + C1) * (sig.x + sig.y + C2);  // >= C1*C2 > 0
    return num * __builtin_amdgcn_rcpf(den);
}

__global__ __launch_bounds__(64, 4)
void ssim_stream_kernel(const float* __restrict__ imgA,
                        const float* __restrict__ imgB,
                        float* __restrict__ ws,
                        float* __restrict__ out)
{
    // Gaussian 11-tap, sigma=1.5, normalized (fp64-computed, verified R1)
    constexpr float GW[11] = {
        0.00102838f, 0.00759880f, 0.03600077f, 0.10936070f, 0.21300554f,
        0.26601173f,
        0.21300554f, 0.10936070f, 0.03600077f, 0.00759880f, 0.00102838f
    };
    const float C1 = 1.01e-4f;   // 0.01^2 + 1e-6
    const float C2 = 9.01e-4f;   // 0.03^2 + 1e-6

    __shared__ float sbuf[2][BUFW];   // 2432 B, row double-buffer, skewed {a,b} pairs

    const int lane = threadIdx.x;
    const int C0 = blockIdx.x * SCOLS;
    const int R0 = blockIdx.y * SROWS;
    const size_t pOff = (size_t)blockIdx.z * (size_t)(IMG * IMG);

    // --- staging task decode (constant per lane) ---
    // 72 float4 tasks per row: t<36 -> imgA quad t ; t>=36 -> imgB quad t-36.
    // Skewed LDS word for col offset xr (= abs col - (C0-8)), img m:
    //   word = 2*(xr + (xr>>4)) + m.  Quad base xr0 = 4q never crosses a
    //   16-col skew block, so the 4 words are wd, wd+2, wd+4, wd+6.
    const int t0   = lane;
    const int q0   = (t0 < 36) ? t0 : (t0 - 36);
    const float* sp0 = ((t0 < 36) ? imgA : imgB) + pOff;
    const int col0 = C0 - 8 + 4 * q0;
    const bool okc0 = (col0 >= 0) && (col0 <= IMG - 4);   // quads never straddle edge
    const int wd0  = 8 * q0 + 2 * (q0 >> 2) + ((t0 < 36) ? 0 : 1);
    const bool has1 = (lane < 8);                          // tasks 64..71: imgB q=28..35
    const int q1   = 28 + lane;
    const int col1 = C0 - 8 + 4 * q1;
    const bool okc1 = (col1 >= 0) && (col1 <= IMG - 4);
    const int wd1  = 8 * q1 + 2 * (q1 >> 2) + 1;
    const float* sp1 = imgB + pOff;

    // --- precomputed skewed read offsets (words) for the 12 window pairs ---
    // pair index pw = 2*lane + 3 + p, word = 2*(pw + (pw>>4)), 8B-aligned.
    int rofs[12];
#pragma unroll
    for (int p = 0; p < 12; ++p) {
        const int pw = 2 * lane + 3 + p;
        rofs[p] = 2 * pw + 2 * (pw >> 4);
    }

    // --- register ring: 11 slots x 2 cols x {h1h2 pair, h11h22 pair, h12} ---
    v2f rA[11][2], rB[11][2];
    float rC[11][2];
#pragma unroll
    for (int i = 0; i < 11; ++i) {
        rA[i][0] = 0; rA[i][1] = 0;
        rB[i][0] = 0; rB[i][1] = 0;
        rC[i][0] = 0; rC[i][1] = 0;
    }

    float lsum = 0.f;
    float4 p0, p1;

#define FETCH(row_) do {                                                      \
        const int ir = (row_);                                                \
        const bool okr = (unsigned)ir < (unsigned)IMG;                        \
        p0 = make_float4(0,0,0,0); p1 = make_float4(0,0,0,0);                 \
        if (okr && okc0) p0 = *(const float4*)(sp0 + (size_t)ir * IMG + col0);\
        if (has1 && okr && okc1)                                              \
            p1 = *(const float4*)(sp1 + (size_t)ir * IMG + col1);             \
    } while (0)

#define STAGE(buf_) do {                                                      \
        float* d0 = &sbuf[buf_][wd0];                                         \
        d0[0] = clamp01(p0.x); d0[2] = clamp01(p0.y);                         \
        d0[4] = clamp01(p0.z); d0[6] = clamp01(p0.w);                         \
        if (has1) {                                                           \
            float* d1 = &sbuf[buf_][wd1];                                     \
            d1[0] = clamp01(p1.x); d1[2] = clamp01(p1.y);                     \
            d1[4] = clamp01(p1.z); d1[6] = clamp01(p1.w);                     \
        }                                                                     \
    } while (0)

    // --- prologue: row for s=0 staged into buf 0; row for s=1 in flight ---
    FETCH(R0 - 5);
    STAGE(0);
    FETCH(R0 - 4);

#pragma unroll 1
    for (int ch = 0; ch < 3; ++ch) {
#pragma unroll
        for (int u = 0; u < 11; ++u) {
            const int s = ch * 11 + u;          // uniform across wave
            if (s < NSTEPS) {
                const int par = s & 1;

                // 1. write-ahead: stage row s+1 (fetched last step) -> buf[par^1]
                if (s + 1 < NSTEPS) STAGE(par ^ 1);

                // 2. prefetch row s+2 (hides HBM/L2 latency behind this step)
                if (s + 2 < NSTEPS) FETCH(R0 - 5 + s + 2);

                // 3. window read (12 skewed v2f) + horizontal conv (packed).
                //    buf[par] was fully written one whole step ago -> no
                //    in-step write->read LDS round trip.
                {
                    const float* sb = &sbuf[par][0];
                    v2f w[12];
#pragma unroll
                    for (int p = 0; p < 12; ++p)
                        w[p] = *(const v2f*)(sb + rofs[p]);

                    v2f hA0 = 0, hB0 = 0, hA1 = 0, hB1 = 0;
                    float hC0 = 0, hC1 = 0;
#pragma unroll
                    for (int j = 0; j < 11; ++j) {
                        const float gj = GW[j];
                        v2f w0 = w[j], w1 = w[j + 1];
                        v2f g0 = gj * w0;            // {g*a, g*b}   pk_mul
                        v2f g1 = gj * w1;
                        hA0 += g0;                   // {h1, h2}     pk_add
                        hA1 += g1;
                        hB0 += g0 * w0;              // {h11, h22}   pk_fma
                        hB1 += g1 * w1;
                        hC0 = fmaf(g0.x, w0.y, hC0); // h12          fma
                        hC1 = fmaf(g1.x, w1.y, hC1);
                    }
                    rA[u][0] = hA0; rA[u][1] = hA1;
                    rB[u][0] = hB0; rB[u][1] = hB1;
                    rC[u][0] = hC0; rC[u][1] = hC1;
                }

                // 4. vertical conv from ring + SSIM (out row R0+s-10)
                if (s >= 10) {
                    v2f vA0 = 0, vB0 = 0, vA1 = 0, vB1 = 0;
                    float vC0 = 0, vC1 = 0;
#pragma unroll
                    for (int i = 0; i < 11; ++i) {
                        const int sl = (u + 1 + i) % 11;   // slot of step s-10+i (static)
                        const float gi = GW[i];
                        vA0 += gi * rA[sl][0]; vA1 += gi * rA[sl][1];
                        vB0 += gi * rB[sl][0]; vB1 += gi * rB[sl][1];
                        vC0 = fmaf(gi, rC[sl][0], vC0);
                        vC1 = fmaf(gi, rC[sl][1], vC1);
                    }
                    lsum += ssim_px(vA0, vB0, vC0, C1, C2);
                    lsum += ssim_px(vA1, vB1, vC1, C1, C2);
                }
            }
        }
    }
#undef FETCH
#undef STAGE

    // wave64 reduce, one atomic per wave
#pragma unroll
    for (int off = 32; off >= 1; off >>= 1)
        lsum += __shfl_down(lsum, off, 64);

    if (lane == 0) {
        atomicAdd(ws, lsum);
        __threadfence();
        unsigned done = atomicAdd(reinterpret_cast<unsigned*>(ws) + 1, 1u);
        if (done == NBLOCKS - 1) {
            __threadfence();
            float total = atomicAdd(ws, 0.0f);   // coherent read-back
            out[0] = 1.0f - total * (1.0f / NPIX);
        }
    }
}

extern "C" void kernel_launch(void* const* d_in, const int* in_sizes, int n_in,
                              void* d_out, int out_size, void* d_ws, size_t ws_size,
                              hipStream_t stream) {
    const float* img1 = (const float*)d_in[0];
    const float* img2 = (const float*)d_in[1];
    float* out = (float*)d_out;
    float* ws  = (float*)d_ws;

    hipMemsetAsync(ws, 0, 2 * sizeof(float), stream);   // {sum, done-counter}

    dim3 grid(IMG / SCOLS, IMG / SROWS, 48);            // 4 x 32 x 48 = 6144 waves
    ssim_stream_kernel<<<grid, 64, 0, stream>>>(img1, img2, ws, out);
}

// Round 3
// 342.743 us; speedup vs baseline: 2.4734x; 2.4734x over previous
//
#include <hip/hip_runtime.h>

// SSIM loss — barrier-free streaming separable conv, v3.
// v2 post-mortem: __launch_bounds__(64,4) capped VGPRs at 64 -> the 110-float
// register ring spilled to scratch (WRITE_SIZE 96KB->404MB, FETCH 87MB->1.09GB,
// 761us). Fix: back to (64,2) (v1's 100-VGPR, spill-free codegen). Keep:
//  - SROWS 16: 6144 one-wave blocks; at ~100 VGPR the HW allows 4 waves/SIMD
//    (16/CU), and 6144/256 = 24/CU feeds that cap (v1's 3072 only reached 12).
//  - Skewed LDS layout (pair xr -> xr + (xr>>4)): measured conflicts/step
//    104 -> 56 in v2 despite the spill.
//  - Write-ahead staging: step s stages row s+1 into buf[par^1], reads
//    buf[par] written a full step earlier -> no in-step LDS round trip.
//  - Finalize fused into stream kernel (last-block-done).

typedef float v2f __attribute__((ext_vector_type(2)));

#define IMG    512
#define SCOLS  128          // cols per strip (2 per lane)
#define SROWS  16           // output rows per strip
#define NSTEPS 26           // SROWS + 10 halo rows
#define BUFW   304          // skewed: 144 pairs + 8 pad pairs = 152 pairs = 304 words
#define NBLOCKS (4 * 32 * 48)
#define NPIX   (16.0f * 3.0f * 512.0f * 512.0f)

__device__ __forceinline__ float clamp01(float x) {
    // fmaxf(NaN,0) -> 0: nan_to_num + clip(0,1) in two ops
    return fminf(fmaxf(x, 0.0f), 1.0f);
}

__device__ __forceinline__ float ssim_px(v2f mu, v2f e, float e12, float C1, float C2) {
    v2f musq = mu * mu;                       // {mu1^2, mu2^2}  (pk_mul)
    float mu12 = mu.x * mu.y;
    v2f sig = e - musq;                       // {sig1, sig2}
    v2f lo = {1e-6f, 1e-6f};
    v2f hi = {1e6f, 1e6f};
    sig = __builtin_elementwise_max(sig, lo);
    sig = __builtin_elementwise_min(sig, hi);
    float s12 = e12 - mu12;
    float num = fmaf(2.f, mu12, C1) * fmaf(2.f, s12, C2);
    float den = (musq.x + musq.y + C1) * (sig.x + sig.y + C2);  // >= C1*C2 > 0
    return num * __builtin_amdgcn_rcpf(den);
}

__global__ __launch_bounds__(64, 2)   // (64,4) spilled the ring — never again
void ssim_stream_kernel(const float* __restrict__ imgA,
                        const float* __restrict__ imgB,
                        float* __restrict__ ws,
                        float* __restrict__ out)
{
    // Gaussian 11-tap, sigma=1.5, normalized (fp64-computed, verified R1)
    constexpr float GW[11] = {
        0.00102838f, 0.00759880f, 0.03600077f, 0.10936070f, 0.21300554f,
        0.26601173f,
        0.21300554f, 0.10936070f, 0.03600077f, 0.00759880f, 0.00102838f
    };
    const float C1 = 1.01e-4f;   // 0.01^2 + 1e-6
    const float C2 = 9.01e-4f;   // 0.03^2 + 1e-6

    __shared__ float sbuf[2][BUFW];   // 2432 B, row double-buffer, skewed {a,b} pairs

    const int lane = threadIdx.x;
    const int C0 = blockIdx.x * SCOLS;
    const int R0 = blockIdx.y * SROWS;
    const size_t pOff = (size_t)blockIdx.z * (size_t)(IMG * IMG);

    // --- staging task decode (constant per lane) ---
    // 72 float4 tasks per row: t<36 -> imgA quad t ; t>=36 -> imgB quad t-36.
    // Skewed LDS word for col offset xr (= abs col - (C0-8)), img m:
    //   word = 2*(xr + (xr>>4)) + m.  Quad base xr0 = 4q never crosses a
    //   16-col skew block, so the 4 words are wd, wd+2, wd+4, wd+6.
    const int t0   = lane;
    const int q0   = (t0 < 36) ? t0 : (t0 - 36);
    const float* sp0 = ((t0 < 36) ? imgA : imgB) + pOff;
    const int col0 = C0 - 8 + 4 * q0;
    const bool okc0 = (col0 >= 0) && (col0 <= IMG - 4);   // quads never straddle edge
    const int wd0  = 8 * q0 + 2 * (q0 >> 2) + ((t0 < 36) ? 0 : 1);
    const bool has1 = (lane < 8);                          // tasks 64..71: imgB q=28..35
    const int q1   = 28 + lane;
    const int col1 = C0 - 8 + 4 * q1;
    const bool okc1 = (col1 >= 0) && (col1 <= IMG - 4);
    const int wd1  = 8 * q1 + 2 * (q1 >> 2) + 1;
    const float* sp1 = imgB + pOff;

    // --- precomputed skewed read offsets (words) for the 12 window pairs ---
    // pair index pw = 2*lane + 3 + p, word = 2*(pw + (pw>>4)), 8B-aligned.
    int rofs[12];
#pragma unroll
    for (int p = 0; p < 12; ++p) {
        const int pw = 2 * lane + 3 + p;
        rofs[p] = 2 * pw + 2 * (pw >> 4);
    }

    // --- register ring: 11 slots x 2 cols x {h1h2 pair, h11h22 pair, h12} ---
    v2f rA[11][2], rB[11][2];
    float rC[11][2];
#pragma unroll
    for (int i = 0; i < 11; ++i) {
        rA[i][0] = 0; rA[i][1] = 0;
        rB[i][0] = 0; rB[i][1] = 0;
        rC[i][0] = 0; rC[i][1] = 0;
    }

    float lsum = 0.f;
    float4 p0, p1;

#define FETCH(row_) do {                                                      \
        const int ir = (row_);                                                \
        const bool okr = (unsigned)ir < (unsigned)IMG;                        \
        p0 = make_float4(0,0,0,0); p1 = make_float4(0,0,0,0);                 \
        if (okr && okc0) p0 = *(const float4*)(sp0 + (size_t)ir * IMG + col0);\
        if (has1 && okr && okc1)                                              \
            p1 = *(const float4*)(sp1 + (size_t)ir * IMG + col1);             \
    } while (0)

#define STAGE(buf_) do {                                                      \
        float* d0 = &sbuf[buf_][wd0];                                         \
        d0[0] = clamp01(p0.x); d0[2] = clamp01(p0.y);                         \
        d0[4] = clamp01(p0.z); d0[6] = clamp01(p0.w);                         \
        if (has1) {                                                           \
            float* d1 = &sbuf[buf_][wd1];                                     \
            d1[0] = clamp01(p1.x); d1[2] = clamp01(p1.y);                     \
            d1[4] = clamp01(p1.z); d1[6] = clamp01(p1.w);                     \
        }                                                                     \
    } while (0)

    // --- prologue: row for s=0 staged into buf 0; row for s=1 in flight ---
    FETCH(R0 - 5);
    STAGE(0);
    FETCH(R0 - 4);

#pragma unroll 1
    for (int ch = 0; ch < 3; ++ch) {
#pragma unroll
        for (int u = 0; u < 11; ++u) {
            const int s = ch * 11 + u;          // uniform across wave
            if (s < NSTEPS) {
                const int par = s & 1;

                // 1. write-ahead: stage row s+1 (fetched last step) -> buf[par^1]
                if (s + 1 < NSTEPS) STAGE(par ^ 1);

                // 2. prefetch row s+2 (hides HBM/L2 latency behind this step)
                if (s + 2 < NSTEPS) FETCH(R0 - 5 + s + 2);

                // 3. window read (12 skewed v2f) + horizontal conv (packed).
                //    buf[par] was fully written one whole step ago -> no
                //    in-step write->read LDS round trip.
                {
                    const float* sb = &sbuf[par][0];
                    v2f w[12];
#pragma unroll
                    for (int p = 0; p < 12; ++p)
                        w[p] = *(const v2f*)(sb + rofs[p]);

                    v2f hA0 = 0, hB0 = 0, hA1 = 0, hB1 = 0;
                    float hC0 = 0, hC1 = 0;
#pragma unroll
                    for (int j = 0; j < 11; ++j) {
                        const float gj = GW[j];
                        v2f w0 = w[j], w1 = w[j + 1];
                        v2f g0 = gj * w0;            // {g*a, g*b}   pk_mul
                        v2f g1 = gj * w1;
                        hA0 += g0;                   // {h1, h2}     pk_add
                        hA1 += g1;
                        hB0 += g0 * w0;              // {h11, h22}   pk_fma
                        hB1 += g1 * w1;
                        hC0 = fmaf(g0.x, w0.y, hC0); // h12          fma
                        hC1 = fmaf(g1.x, w1.y, hC1);
                    }
                    rA[u][0] = hA0; rA[u][1] = hA1;
                    rB[u][0] = hB0; rB[u][1] = hB1;
                    rC[u][0] = hC0; rC[u][1] = hC1;
                }

                // 4. vertical conv from ring + SSIM (out row R0+s-10)
                if (s >= 10) {
                    v2f vA0 = 0, vB0 = 0, vA1 = 0, vB1 = 0;
                    float vC0 = 0, vC1 = 0;
#pragma unroll
                    for (int i = 0; i < 11; ++i) {
                        const int sl = (u + 1 + i) % 11;   // slot of step s-10+i (static)
                        const float gi = GW[i];
                        vA0 += gi * rA[sl][0]; vA1 += gi * rA[sl][1];
                        vB0 += gi * rB[sl][0]; vB1 += gi * rB[sl][1];
                        vC0 = fmaf(gi, rC[sl][0], vC0);
                        vC1 = fmaf(gi, rC[sl][1], vC1);
                    }
                    lsum += ssim_px(vA0, vB0, vC0, C1, C2);
                    lsum += ssim_px(vA1, vB1, vC1, C1, C2);
                }
            }
        }
    }
#undef FETCH
#undef STAGE

    // wave64 reduce, one atomic per wave
#pragma unroll
    for (int off = 32; off >= 1; off >>= 1)
        lsum += __shfl_down(lsum, off, 64);

    if (lane == 0) {
        atomicAdd(ws, lsum);
        __threadfence();
        unsigned done = atomicAdd(reinterpret_cast<unsigned*>(ws) + 1, 1u);
        if (done == NBLOCKS - 1) {
            __threadfence();
            float total = atomicAdd(ws, 0.0f);   // coherent read-back
            out[0] = 1.0f - total * (1.0f / NPIX);
        }
    }
}

extern "C" void kernel_launch(void* const* d_in, const int* in_sizes, int n_in,
                              void* d_out, int out_size, void* d_ws, size_t ws_size,
                              hipStream_t stream) {
    const float* img1 = (const float*)d_in[0];
    const float* img2 = (const float*)d_in[1];
    float* out = (float*)d_out;
    float* ws  = (float*)d_ws;

    hipMemsetAsync(ws, 0, 2 * sizeof(float), stream);   // {sum, done-counter}

    dim3 grid(IMG / SCOLS, IMG / SROWS, 48);            // 4 x 32 x 48 = 6144 waves
    ssim_stream_kernel<<<grid, 64, 0, stream>>>(img1, img2, ws, out);
}